// Round 1
// baseline (631.191 us; speedup 1.0000x reference)
//
#include <hip/hip_runtime.h>
#include <stdint.h>

// Permutohedral splat: N=262144 points, D=3, V=64, CAPACITY=2^20.
// Output table: [CAPACITY, 65] float32 = 272.6 MB.
// One wave (64 lanes) per point; lane v owns value channel v.

#define CAPACITY (1u << 20)
#define TBL_W 65

__global__ __launch_bounds__(256) void splat_kernel(
    const float* __restrict__ pos,
    const float* __restrict__ vals,
    float* __restrict__ table,
    int n)
{
    const int gtid  = blockIdx.x * blockDim.x + threadIdx.x;
    const int point = gtid >> 6;
    const int lane  = threadIdx.x & 63;
    if (point >= n) return;

    // scale = inv_std / sqrt((i+1)(i+2)), inv_std = sqrt(2/3)*4, double-rounded to f32
    const float scale0 = 2.3094010767585034f;
    const float scale1 = 1.3333333333333333f;
    const float scale2 = 0.9428090415820634f;

    const float cf0 = pos[point * 3 + 0] * scale0;
    const float cf1 = pos[point * 3 + 1] * scale1;
    const float cf2 = pos[point * 3 + 2] * scale2;

    // Elevation, matching JAX cumsum order: suf1 = cf2+cf1; suf0 = suf1+cf0
    const float t1 = cf2 + cf1;
    float elev[4];
    elev[0] = t1 + cf0;
    elev[1] = t1 - cf0;
    elev[2] = cf2 - 2.0f * cf1;
    elev[3] = -3.0f * cf2;

    float rem0[4];
    float rd_s = 0.0f;
#pragma unroll
    for (int j = 0; j < 4; ++j) {
        float rd = rintf(elev[j] * 0.25f);   // round-half-even == jnp.round; /4 exact
        rem0[j] = rd * 4.0f;
        rd_s += rd;
    }
    const int rd_sum = (int)rd_s;            // exact small integer

    float diff[4];
#pragma unroll
    for (int j = 0; j < 4; ++j) diff[j] = elev[j] - rem0[j];

    int rank[4];
#pragma unroll
    for (int i = 0; i < 4; ++i) {
        int r = 0;
#pragma unroll
        for (int j = 0; j < 4; ++j) {
            if (diff[j] > diff[i] || (diff[j] == diff[i] && j < i)) r++;
        }
        rank[i] = r + rd_sum;
    }

    // under/over adjustment (per coordinate)
#pragma unroll
    for (int i = 0; i < 4; ++i) {
        if (rank[i] < 0)      { rank[i] += 4; rem0[i] += 4.0f; }
        else if (rank[i] > 3) { rank[i] -= 4; rem0[i] -= 4.0f; }
    }

    float delta[4];
#pragma unroll
    for (int i = 0; i < 4; ++i) delta[i] = (elev[i] - rem0[i]) * 0.25f;

    // bary via one-hot scatter (guard out-of-range like jax.nn.one_hot)
    float b[5] = {0.f, 0.f, 0.f, 0.f, 0.f};
#pragma unroll
    for (int i = 0; i < 4; ++i) {
        int k1 = 3 - rank[i];
        int k2 = 4 - rank[i];
        if (k1 >= 0 && k1 < 5) b[k1] += delta[i];
        if (k2 >= 0 && k2 < 5) b[k2] -= delta[i];
    }
    float w[4];
    w[0] = b[0] + (1.0f + b[4]);   // ref ordering: bary[0] += 1.0 + bary[4]
    w[1] = b[1];
    w[2] = b[2];
    w[3] = b[3];

    // hash for each of the 4 simplex vertices
    const uint32_t P0 = 2654435761u, P1 = 805459861u, P2 = 3674653429u;
    const int k0 = (int)rem0[0];   // truncating f32->i32 == astype(int32); exact int
    const int k1i = (int)rem0[1];
    const int k2i = (int)rem0[2];

    uint32_t h[4];
#pragma unroll
    for (int r = 0; r < 4; ++r) {
        int o0 = (rank[0] < 4 - r) ? r : r - 4;
        int o1 = (rank[1] < 4 - r) ? r : r - 4;
        int o2 = (rank[2] < 4 - r) ? r : r - 4;
        uint32_t hh = (uint32_t)(k0 + o0) * P0
                    + (uint32_t)(k1i + o1) * P1
                    + (uint32_t)(k2i + o2) * P2;
        h[r] = hh & (CAPACITY - 1u);
    }

    // scatter-add: lane v handles channel v; lane 0 also the homogeneous channel
    const float v = vals[(size_t)point * 64 + lane];
#pragma unroll
    for (int r = 0; r < 4; ++r) {
        atomicAdd(&table[(size_t)h[r] * TBL_W + lane], w[r] * v);
    }
    if (lane == 0) {
#pragma unroll
        for (int r = 0; r < 4; ++r) {
            atomicAdd(&table[(size_t)h[r] * TBL_W + 64], w[r]);
        }
    }
}

extern "C" void kernel_launch(void* const* d_in, const int* in_sizes, int n_in,
                              void* d_out, int out_size, void* d_ws, size_t ws_size,
                              hipStream_t stream) {
    const float* pos  = (const float*)d_in[0];
    const float* vals = (const float*)d_in[1];
    float* table      = (float*)d_out;

    const int n = in_sizes[0] / 3;   // 262144 points

    // Zero the output table every launch (harness poisons, never re-poisons).
    hipMemsetAsync(d_out, 0, (size_t)out_size * sizeof(float), stream);

    const int threads = 256;                 // 4 waves/block, 1 point/wave
    const int blocks  = (n * 64 + threads - 1) / threads;
    splat_kernel<<<blocks, threads, 0, stream>>>(pos, vals, table, n);
}

// Round 2
// 557.412 us; speedup vs baseline: 1.1324x; 1.1324x over previous
//
#include <hip/hip_runtime.h>
#include <stdint.h>

// Permutohedral splat via counting-sort aggregation.
// N=262144 points, D=3, V=64, CAPACITY=2^20, table [CAPACITY,65] f32.
//
// Pipeline: histogram (1 inc per point-vertex) -> exclusive scan of 1M
// counters -> scatter (h, w, pid) sorted by hash -> windowed wave reduce
// (lane v owns channel v) with one vector atomicAdd per run boundary.

#define CAPACITY (1u << 20)
#define TBL_W 65
#define WINDOW 256

// ---------------- shared lattice math (validated in round 0) ----------------
__device__ __forceinline__ void lattice_point(const float* __restrict__ pos, int point,
                                              uint32_t h[4], float w[4])
{
    const float scale0 = 2.3094010767585034f;
    const float scale1 = 1.3333333333333333f;
    const float scale2 = 0.9428090415820634f;

    const float cf0 = pos[point * 3 + 0] * scale0;
    const float cf1 = pos[point * 3 + 1] * scale1;
    const float cf2 = pos[point * 3 + 2] * scale2;

    const float t1 = cf2 + cf1;
    float elev[4];
    elev[0] = t1 + cf0;
    elev[1] = t1 - cf0;
    elev[2] = cf2 - 2.0f * cf1;
    elev[3] = -3.0f * cf2;

    float rem0[4];
    float rd_s = 0.0f;
#pragma unroll
    for (int j = 0; j < 4; ++j) {
        float rd = rintf(elev[j] * 0.25f);
        rem0[j] = rd * 4.0f;
        rd_s += rd;
    }
    const int rd_sum = (int)rd_s;

    float diff[4];
#pragma unroll
    for (int j = 0; j < 4; ++j) diff[j] = elev[j] - rem0[j];

    int rank[4];
#pragma unroll
    for (int i = 0; i < 4; ++i) {
        int r = 0;
#pragma unroll
        for (int j = 0; j < 4; ++j) {
            if (diff[j] > diff[i] || (diff[j] == diff[i] && j < i)) r++;
        }
        rank[i] = r + rd_sum;
    }

#pragma unroll
    for (int i = 0; i < 4; ++i) {
        if (rank[i] < 0)      { rank[i] += 4; rem0[i] += 4.0f; }
        else if (rank[i] > 3) { rank[i] -= 4; rem0[i] -= 4.0f; }
    }

    float delta[4];
#pragma unroll
    for (int i = 0; i < 4; ++i) delta[i] = (elev[i] - rem0[i]) * 0.25f;

    float b[5] = {0.f, 0.f, 0.f, 0.f, 0.f};
#pragma unroll
    for (int i = 0; i < 4; ++i) {
        int k1 = 3 - rank[i];
        int k2 = 4 - rank[i];
        if (k1 >= 0 && k1 < 5) b[k1] += delta[i];
        if (k2 >= 0 && k2 < 5) b[k2] -= delta[i];
    }
    w[0] = b[0] + (1.0f + b[4]);
    w[1] = b[1];
    w[2] = b[2];
    w[3] = b[3];

    const uint32_t P0 = 2654435761u, P1 = 805459861u, P2 = 3674653429u;
    const int k0  = (int)rem0[0];
    const int k1i = (int)rem0[1];
    const int k2i = (int)rem0[2];

#pragma unroll
    for (int r = 0; r < 4; ++r) {
        int o0 = (rank[0] < 4 - r) ? r : r - 4;
        int o1 = (rank[1] < 4 - r) ? r : r - 4;
        int o2 = (rank[2] < 4 - r) ? r : r - 4;
        uint32_t hh = (uint32_t)(k0 + o0)  * P0
                    + (uint32_t)(k1i + o1) * P1
                    + (uint32_t)(k2i + o2) * P2;
        h[r] = hh & (CAPACITY - 1u);
    }
}

// ---------------- pipeline kernels ----------------
__global__ __launch_bounds__(256) void k_hist(const float* __restrict__ pos,
                                              uint32_t* __restrict__ counts, int n)
{
    int p = blockIdx.x * blockDim.x + threadIdx.x;
    if (p >= n) return;
    uint32_t h[4]; float w[4];
    lattice_point(pos, p, h, w);
#pragma unroll
    for (int r = 0; r < 4; ++r) atomicAdd(&counts[h[r]], 1u);
}

__global__ __launch_bounds__(256) void k_blocksum(const uint32_t* __restrict__ counts,
                                                  uint32_t* __restrict__ partials)
{
    __shared__ uint32_t s[256];
    const int b = blockIdx.x, t = threadIdx.x;
    uint4 v = ((const uint4*)(counts + (size_t)b * 1024))[t];
    s[t] = v.x + v.y + v.z + v.w;
    __syncthreads();
    for (int o = 128; o > 0; o >>= 1) {
        if (t < o) s[t] += s[t + o];
        __syncthreads();
    }
    if (t == 0) partials[b] = s[0];
}

__global__ __launch_bounds__(1024) void k_scanpartials(uint32_t* __restrict__ partials)
{
    __shared__ uint32_t s[1024];
    const int t = threadIdx.x;
    s[t] = partials[t];
    __syncthreads();
    for (int o = 1; o < 1024; o <<= 1) {
        uint32_t x = s[t];
        uint32_t y = (t >= o) ? s[t - o] : 0u;
        __syncthreads();
        s[t] = x + y;
        __syncthreads();
    }
    partials[t] = (t > 0) ? s[t - 1] : 0u;   // exclusive
}

__global__ __launch_bounds__(256) void k_offsets(const uint32_t* __restrict__ counts,
                                                 const uint32_t* __restrict__ partials,
                                                 uint32_t* __restrict__ offsets)
{
    __shared__ uint32_t s[256];
    const int b = blockIdx.x, t = threadIdx.x;
    uint4 v = ((const uint4*)(counts + (size_t)b * 1024))[t];
    const uint32_t s4 = v.x + v.y + v.z + v.w;
    s[t] = s4;
    __syncthreads();
    for (int o = 1; o < 256; o <<= 1) {
        uint32_t x = s[t];
        uint32_t y = (t >= o) ? s[t - o] : 0u;
        __syncthreads();
        s[t] = x + y;
        __syncthreads();
    }
    uint32_t texcl = ((t > 0) ? s[t - 1] : 0u) + partials[b];
    uint4 o4;
    o4.x = texcl;
    o4.y = texcl + v.x;
    o4.z = o4.y + v.y;
    o4.w = o4.z + v.z;
    ((uint4*)(offsets + (size_t)b * 1024))[t] = o4;
}

__global__ __launch_bounds__(256) void k_scatter(const float* __restrict__ pos,
                                                 const uint32_t* __restrict__ offsets,
                                                 uint32_t* __restrict__ counts2,
                                                 uint32_t* __restrict__ h_s,
                                                 uint2* __restrict__ wp_s, int n)
{
    int p = blockIdx.x * blockDim.x + threadIdx.x;
    if (p >= n) return;
    uint32_t h[4]; float w[4];
    lattice_point(pos, p, h, w);
#pragma unroll
    for (int r = 0; r < 4; ++r) {
        uint32_t slotpos = atomicAdd(&counts2[h[r]], 1u);
        uint32_t dst = offsets[h[r]] + slotpos;
        h_s[dst] = h[r];
        uint2 wp;
        wp.x = __float_as_uint(w[r]);
        wp.y = (uint32_t)p;
        wp_s[dst] = wp;
    }
}

__global__ __launch_bounds__(256) void k_reduce(const uint32_t* __restrict__ h_s,
                                                const uint2* __restrict__ wp_s,
                                                const float* __restrict__ vals,
                                                float* __restrict__ table, int M)
{
    const int gtid = blockIdx.x * blockDim.x + threadIdx.x;
    const int wid  = gtid >> 6;
    const int lane = threadIdx.x & 63;
    const int e0 = wid * WINDOW;
    if (e0 >= M) return;
    const int e1 = min(e0 + WINDOW, M);

    uint32_t hprev = h_s[e0];
    float acc = 0.0f, acc1 = 0.0f;
    for (int e = e0; e < e1; ++e) {
        const uint32_t h = h_s[e];
        if (h != hprev) {
            atomicAdd(&table[(size_t)hprev * TBL_W + lane], acc);
            if (lane == 0) atomicAdd(&table[(size_t)hprev * TBL_W + 64], acc1);
            acc = 0.0f; acc1 = 0.0f;
            hprev = h;
        }
        const uint2 wp = wp_s[e];
        const float wgt = __uint_as_float(wp.x);
        acc  += wgt * vals[(size_t)wp.y * 64 + lane];
        acc1 += wgt;
    }
    atomicAdd(&table[(size_t)hprev * TBL_W + lane], acc);
    if (lane == 0) atomicAdd(&table[(size_t)hprev * TBL_W + 64], acc1);
}

// ---------------- round-0 fallback (used only if ws too small) ----------------
__global__ __launch_bounds__(256) void splat_fallback(const float* __restrict__ pos,
                                                      const float* __restrict__ vals,
                                                      float* __restrict__ table, int n)
{
    const int gtid  = blockIdx.x * blockDim.x + threadIdx.x;
    const int point = gtid >> 6;
    const int lane  = threadIdx.x & 63;
    if (point >= n) return;
    uint32_t h[4]; float w[4];
    lattice_point(pos, point, h, w);
    const float v = vals[(size_t)point * 64 + lane];
#pragma unroll
    for (int r = 0; r < 4; ++r)
        atomicAdd(&table[(size_t)h[r] * TBL_W + lane], w[r] * v);
    if (lane == 0) {
#pragma unroll
        for (int r = 0; r < 4; ++r)
            atomicAdd(&table[(size_t)h[r] * TBL_W + 64], w[r]);
    }
}

// ---------------- host launch ----------------
extern "C" void kernel_launch(void* const* d_in, const int* in_sizes, int n_in,
                              void* d_out, int out_size, void* d_ws, size_t ws_size,
                              hipStream_t stream) {
    const float* pos  = (const float*)d_in[0];
    const float* vals = (const float*)d_in[1];
    float* table      = (float*)d_out;

    const int n = in_sizes[0] / 3;       // 262144
    const int M = n * 4;                 // 1,048,576 entries

    // Zero output table every launch.
    hipMemsetAsync(d_out, 0, (size_t)out_size * sizeof(float), stream);

    // Workspace layout (bytes):
    const size_t SZ_CNT  = (size_t)CAPACITY * 4;          // 4 MB
    const size_t OFF_CNT  = 0;
    const size_t OFF_CNT2 = OFF_CNT  + SZ_CNT;            // 4 MB
    const size_t OFF_OFFS = OFF_CNT2 + SZ_CNT;            // 8 MB
    const size_t OFF_PART = OFF_OFFS + SZ_CNT;            // 12 MB
    const size_t OFF_HS   = OFF_PART + 65536;             // 12 MB + 64 KB
    const size_t OFF_WP   = OFF_HS   + (size_t)M * 4;
    const size_t REQUIRED = OFF_WP   + (size_t)M * 8;

    if (ws_size < REQUIRED) {
        const int threads = 256;
        const int blocks  = (n * 64 + threads - 1) / threads;
        splat_fallback<<<blocks, threads, 0, stream>>>(pos, vals, table, n);
        return;
    }

    uint8_t* ws = (uint8_t*)d_ws;
    uint32_t* counts   = (uint32_t*)(ws + OFF_CNT);
    uint32_t* counts2  = (uint32_t*)(ws + OFF_CNT2);
    uint32_t* offsets  = (uint32_t*)(ws + OFF_OFFS);
    uint32_t* partials = (uint32_t*)(ws + OFF_PART);
    uint32_t* h_s      = (uint32_t*)(ws + OFF_HS);
    uint2*    wp_s     = (uint2*)   (ws + OFF_WP);

    // Zero both counter arrays.
    hipMemsetAsync(ws, 0, 2 * SZ_CNT, stream);

    const int ptBlocks = (n + 255) / 256;
    k_hist<<<ptBlocks, 256, 0, stream>>>(pos, counts, n);

    k_blocksum    <<<CAPACITY / 1024, 256,  0, stream>>>(counts, partials);
    k_scanpartials<<<1,              1024, 0, stream>>>(partials);
    k_offsets     <<<CAPACITY / 1024, 256,  0, stream>>>(counts, partials, offsets);

    k_scatter<<<ptBlocks, 256, 0, stream>>>(pos, offsets, counts2, h_s, wp_s, n);

    const int nWaves  = (M + WINDOW - 1) / WINDOW;     // 4096 waves
    const int rBlocks = (nWaves * 64 + 255) / 256;     // 1024 blocks
    k_reduce<<<rBlocks, 256, 0, stream>>>(h_s, wp_s, vals, table, M);
}

// Round 3
// 448.750 us; speedup vs baseline: 1.4066x; 1.2421x over previous
//
#include <hip/hip_runtime.h>
#include <stdint.h>

// Permutohedral splat via replicated counting-sort + branch-free segmented reduce.
// N=262144 points, D=3, V=64, CAPACITY=2^20, table [CAPACITY,65] f32.

#define CAPACITY (1u << 20)
#define TBL_W 65
#define CHUNK 128

// ---------------- lattice math (validated round 0/1) ----------------
__device__ __forceinline__ void lattice_point(const float* __restrict__ pos, int point,
                                              uint32_t h[4], float w[4])
{
    const float scale0 = 2.3094010767585034f;
    const float scale1 = 1.3333333333333333f;
    const float scale2 = 0.9428090415820634f;

    const float cf0 = pos[point * 3 + 0] * scale0;
    const float cf1 = pos[point * 3 + 1] * scale1;
    const float cf2 = pos[point * 3 + 2] * scale2;

    const float t1 = cf2 + cf1;
    float elev[4];
    elev[0] = t1 + cf0;
    elev[1] = t1 - cf0;
    elev[2] = cf2 - 2.0f * cf1;
    elev[3] = -3.0f * cf2;

    float rem0[4];
    float rd_s = 0.0f;
#pragma unroll
    for (int j = 0; j < 4; ++j) {
        float rd = rintf(elev[j] * 0.25f);
        rem0[j] = rd * 4.0f;
        rd_s += rd;
    }
    const int rd_sum = (int)rd_s;

    float diff[4];
#pragma unroll
    for (int j = 0; j < 4; ++j) diff[j] = elev[j] - rem0[j];

    int rank[4];
#pragma unroll
    for (int i = 0; i < 4; ++i) {
        int r = 0;
#pragma unroll
        for (int j = 0; j < 4; ++j) {
            if (diff[j] > diff[i] || (diff[j] == diff[i] && j < i)) r++;
        }
        rank[i] = r + rd_sum;
    }

#pragma unroll
    for (int i = 0; i < 4; ++i) {
        if (rank[i] < 0)      { rank[i] += 4; rem0[i] += 4.0f; }
        else if (rank[i] > 3) { rank[i] -= 4; rem0[i] -= 4.0f; }
    }

    float delta[4];
#pragma unroll
    for (int i = 0; i < 4; ++i) delta[i] = (elev[i] - rem0[i]) * 0.25f;

    float b[5] = {0.f, 0.f, 0.f, 0.f, 0.f};
#pragma unroll
    for (int i = 0; i < 4; ++i) {
        int k1 = 3 - rank[i];
        int k2 = 4 - rank[i];
        if (k1 >= 0 && k1 < 5) b[k1] += delta[i];
        if (k2 >= 0 && k2 < 5) b[k2] -= delta[i];
    }
    w[0] = b[0] + (1.0f + b[4]);
    w[1] = b[1];
    w[2] = b[2];
    w[3] = b[3];

    const uint32_t P0 = 2654435761u, P1 = 805459861u, P2 = 3674653429u;
    const int k0  = (int)rem0[0];
    const int k1i = (int)rem0[1];
    const int k2i = (int)rem0[2];

#pragma unroll
    for (int r = 0; r < 4; ++r) {
        int o0 = (rank[0] < 4 - r) ? r : r - 4;
        int o1 = (rank[1] < 4 - r) ? r : r - 4;
        int o2 = (rank[2] < 4 - r) ? r : r - 4;
        uint32_t hh = (uint32_t)(k0 + o0)  * P0
                    + (uint32_t)(k1i + o1) * P1
                    + (uint32_t)(k2i + o2) * P2;
        h[r] = hh & (CAPACITY - 1u);
    }
}

// ---------------- pipeline kernels ----------------
// counts laid out rep-major: counts[rep*CAPACITY + h]; rep = point & (R-1).
__global__ __launch_bounds__(256) void k_hist(const float* __restrict__ pos,
                                              uint32_t* __restrict__ counts,
                                              int n, int Rmask)
{
    int p = blockIdx.x * blockDim.x + threadIdx.x;
    if (p >= n) return;
    uint32_t h[4]; float w[4];
    lattice_point(pos, p, h, w);
    const size_t repBase = (size_t)(p & Rmask) * CAPACITY;
#pragma unroll
    for (int r = 0; r < 4; ++r) atomicAdd(&counts[repBase + h[r]], 1u);
}

__global__ __launch_bounds__(256) void k_blocksum(const uint32_t* __restrict__ counts,
                                                  uint32_t* __restrict__ partials)
{
    __shared__ uint32_t s[256];
    const int b = blockIdx.x, t = threadIdx.x;
    uint4 v = ((const uint4*)(counts + (size_t)b * 1024))[t];
    s[t] = v.x + v.y + v.z + v.w;
    __syncthreads();
    for (int o = 128; o > 0; o >>= 1) {
        if (t < o) s[t] += s[t + o];
        __syncthreads();
    }
    if (t == 0) partials[b] = s[0];
}

// Exclusive scan of npart (= 1024*R <= 8192) partials, single block of 1024.
__global__ __launch_bounds__(1024) void k_scanpartials(uint32_t* __restrict__ partials,
                                                       int npart)
{
    __shared__ uint32_t s[1024];
    const int t = threadIdx.x;
    const int k = npart >> 10;           // elems per thread (1..8)
    uint32_t v[8];
    uint32_t tot = 0;
    for (int j = 0; j < k; ++j) { v[j] = partials[t * k + j]; tot += v[j]; }
    s[t] = tot;
    __syncthreads();
    for (int o = 1; o < 1024; o <<= 1) {
        uint32_t x = s[t];
        uint32_t y = (t >= o) ? s[t - o] : 0u;
        __syncthreads();
        s[t] = x + y;
        __syncthreads();
    }
    uint32_t run = (t > 0) ? s[t - 1] : 0u;   // exclusive across threads
    for (int j = 0; j < k; ++j) {
        uint32_t tmp = v[j];
        partials[t * k + j] = run;
        run += tmp;
    }
}

__global__ __launch_bounds__(256) void k_offsets(const uint32_t* __restrict__ counts,
                                                 const uint32_t* __restrict__ partials,
                                                 uint32_t* __restrict__ offsets)
{
    __shared__ uint32_t s[256];
    const int b = blockIdx.x, t = threadIdx.x;
    uint4 v = ((const uint4*)(counts + (size_t)b * 1024))[t];
    const uint32_t s4 = v.x + v.y + v.z + v.w;
    s[t] = s4;
    __syncthreads();
    for (int o = 1; o < 256; o <<= 1) {
        uint32_t x = s[t];
        uint32_t y = (t >= o) ? s[t - o] : 0u;
        __syncthreads();
        s[t] = x + y;
        __syncthreads();
    }
    uint32_t texcl = ((t > 0) ? s[t - 1] : 0u) + partials[b];
    uint4 o4;
    o4.x = texcl;
    o4.y = texcl + v.x;
    o4.z = o4.y + v.y;
    o4.w = o4.z + v.z;
    ((uint4*)(offsets + (size_t)b * 1024))[t] = o4;
}

// Build chunked worklist from offsets: one item per (run-chunk of <=CHUNK entries).
__global__ __launch_bounds__(256) void k_worklist(const uint32_t* __restrict__ offsets,
                                                  uint4* __restrict__ work,
                                                  uint32_t* __restrict__ cursor,
                                                  uint32_t L, uint32_t M, uint32_t wcap)
{
    uint32_t lin = blockIdx.x * blockDim.x + threadIdx.x;
    if (lin >= L) return;
    uint32_t start = offsets[lin];
    uint32_t end   = (lin + 1 < L) ? offsets[lin + 1] : M;
    uint32_t cnt = end - start;
    if (cnt == 0) return;
    uint32_t h = lin & (CAPACITY - 1u);
    uint32_t nch = (cnt + CHUNK - 1) / CHUNK;
    uint32_t base = atomicAdd(cursor, nch);
    for (uint32_t c = 0; c < nch; ++c) {
        uint32_t idx = base + c;
        if (idx >= wcap) break;
        uint32_t cs = start + c * CHUNK;
        uint32_t ce = min(cs + CHUNK, end);
        work[idx] = make_uint4(h, cs, ce, 0u);
    }
}

// Scatter (w, pid) into sorted position; atomicSub consumes counts (no 2nd array).
__global__ __launch_bounds__(256) void k_scatter(const float* __restrict__ pos,
                                                 const uint32_t* __restrict__ offsets,
                                                 uint32_t* __restrict__ counts,
                                                 uint2* __restrict__ wp_s,
                                                 int n, int Rmask)
{
    int p = blockIdx.x * blockDim.x + threadIdx.x;
    if (p >= n) return;
    uint32_t h[4]; float w[4];
    lattice_point(pos, p, h, w);
    const size_t repBase = (size_t)(p & Rmask) * CAPACITY;
#pragma unroll
    for (int r = 0; r < 4; ++r) {
        const size_t lin = repBase + h[r];
        uint32_t slot = atomicSub(&counts[lin], 1u) - 1u;
        uint32_t dst  = offsets[lin] + slot;
        uint2 wp;
        wp.x = __float_as_uint(w[r]);
        wp.y = (uint32_t)p;
        wp_s[dst] = wp;
    }
}

// One wave per work item; branch-free accumulate; one vector atomic flush.
__global__ __launch_bounds__(256) void k_reduce(const uint4* __restrict__ work,
                                                const uint32_t* __restrict__ cursor,
                                                const uint2* __restrict__ wp_s,
                                                const float* __restrict__ vals,
                                                float* __restrict__ table,
                                                uint32_t wcap)
{
    const int gtid   = blockIdx.x * blockDim.x + threadIdx.x;
    const int wid    = gtid >> 6;
    const int lane   = threadIdx.x & 63;
    const int nwaves = (gridDim.x * blockDim.x) >> 6;
    const uint32_t nwork = min(*cursor, wcap);

    for (uint32_t it = wid; it < nwork; it += nwaves) {
        const uint4 wi = work[it];
        const uint32_t h = wi.x;
        uint32_t e = wi.y;
        const uint32_t end = wi.z;

        float acc = 0.0f, acc1 = 0.0f;
        for (; e + 4 <= end; e += 4) {
            const uint2 a0 = wp_s[e + 0];
            const uint2 a1 = wp_s[e + 1];
            const uint2 a2 = wp_s[e + 2];
            const uint2 a3 = wp_s[e + 3];
            const float w0 = __uint_as_float(a0.x);
            const float w1 = __uint_as_float(a1.x);
            const float w2 = __uint_as_float(a2.x);
            const float w3 = __uint_as_float(a3.x);
            const float v0 = vals[(size_t)a0.y * 64 + lane];
            const float v1 = vals[(size_t)a1.y * 64 + lane];
            const float v2 = vals[(size_t)a2.y * 64 + lane];
            const float v3 = vals[(size_t)a3.y * 64 + lane];
            acc  += w0 * v0 + w1 * v1 + w2 * v2 + w3 * v3;
            acc1 += w0 + w1 + w2 + w3;
        }
        for (; e < end; ++e) {
            const uint2 a = wp_s[e];
            const float wgt = __uint_as_float(a.x);
            acc  += wgt * vals[(size_t)a.y * 64 + lane];
            acc1 += wgt;
        }
        atomicAdd(&table[(size_t)h * TBL_W + lane], acc);
        if (lane == 0) atomicAdd(&table[(size_t)h * TBL_W + 64], acc1);
    }
}

// ---------------- round-0 fallback ----------------
__global__ __launch_bounds__(256) void splat_fallback(const float* __restrict__ pos,
                                                      const float* __restrict__ vals,
                                                      float* __restrict__ table, int n)
{
    const int gtid  = blockIdx.x * blockDim.x + threadIdx.x;
    const int point = gtid >> 6;
    const int lane  = threadIdx.x & 63;
    if (point >= n) return;
    uint32_t h[4]; float w[4];
    lattice_point(pos, point, h, w);
    const float v = vals[(size_t)point * 64 + lane];
#pragma unroll
    for (int r = 0; r < 4; ++r)
        atomicAdd(&table[(size_t)h[r] * TBL_W + lane], w[r] * v);
    if (lane == 0) {
#pragma unroll
        for (int r = 0; r < 4; ++r)
            atomicAdd(&table[(size_t)h[r] * TBL_W + 64], w[r]);
    }
}

// ---------------- host launch ----------------
extern "C" void kernel_launch(void* const* d_in, const int* in_sizes, int n_in,
                              void* d_out, int out_size, void* d_ws, size_t ws_size,
                              hipStream_t stream) {
    const float* pos  = (const float*)d_in[0];
    const float* vals = (const float*)d_in[1];
    float* table      = (float*)d_out;

    const int n = in_sizes[0] / 3;        // 262144
    const uint32_t M = (uint32_t)n * 4;   // 1,048,576

    hipMemsetAsync(d_out, 0, (size_t)out_size * sizeof(float), stream);

    // Choose replication R and worklist capacity to fit ws.
    int R = 0;
    uint32_t wcap = 0;
    size_t offCnt = 0, offCur = 0, offOff = 0, offPart = 0, offWp = 0, offWork = 0;
    const uint32_t wcapFull  = M + M / CHUNK;   // safe upper bound
    const uint32_t wcapSmall = 1u << 16;
    for (int tryR = 8; tryR >= 1; tryR >>= 1) {
        for (int tryW = 0; tryW < 2; ++tryW) {
            uint32_t wc = tryW ? wcapSmall : wcapFull;
            size_t L = (size_t)CAPACITY * tryR;
            size_t o0 = 0;                       // counts: L*4
            size_t o1 = o0 + L * 4;              // cursor: 64
            size_t o2 = o1 + 64;                 // offsets: L*4
            size_t o3 = o2 + L * 4;              // partials: (L/1024)*4
            size_t o4 = o3 + (L / 1024) * 4;     // wp_s: M*8
            size_t o5 = o4 + (size_t)M * 8;      // work: wc*16
            size_t need = o5 + (size_t)wc * 16;
            if (need <= ws_size) {
                R = tryR; wcap = wc;
                offCnt = o0; offCur = o1; offOff = o2; offPart = o3; offWp = o4; offWork = o5;
                break;
            }
        }
        if (R) break;
    }

    if (!R) {
        const int blocks = (n * 64 + 255) / 256;
        splat_fallback<<<blocks, 256, 0, stream>>>(pos, vals, table, n);
        return;
    }

    uint8_t* ws = (uint8_t*)d_ws;
    uint32_t* counts   = (uint32_t*)(ws + offCnt);
    uint32_t* cursor   = (uint32_t*)(ws + offCur);
    uint32_t* offsets  = (uint32_t*)(ws + offOff);
    uint32_t* partials = (uint32_t*)(ws + offPart);
    uint2*    wp_s     = (uint2*)   (ws + offWp);
    uint4*    work     = (uint4*)   (ws + offWork);

    const uint32_t L = (uint32_t)CAPACITY * R;
    const int Rmask = R - 1;

    // Zero counts + cursor in one memset.
    hipMemsetAsync(ws, 0, (size_t)L * 4 + 64, stream);

    const int ptBlocks = (n + 255) / 256;
    k_hist<<<ptBlocks, 256, 0, stream>>>(pos, counts, n, Rmask);

    const int scanBlocks = L / 1024;
    k_blocksum    <<<scanBlocks, 256,  0, stream>>>(counts, partials);
    k_scanpartials<<<1,          1024, 0, stream>>>(partials, scanBlocks);
    k_offsets     <<<scanBlocks, 256,  0, stream>>>(counts, partials, offsets);

    k_worklist<<<(L + 255) / 256, 256, 0, stream>>>(offsets, work, cursor, L, M, wcap);
    k_scatter <<<ptBlocks,        256, 0, stream>>>(pos, offsets, counts, wp_s, n, Rmask);

    k_reduce<<<8192, 256, 0, stream>>>(work, cursor, wp_s, vals, table, wcap);
}

// Round 4
// 321.552 us; speedup vs baseline: 1.9630x; 1.3956x over previous
//
#include <hip/hip_runtime.h>
#include <stdint.h>

// Permutohedral splat via replicated counting-sort + shfl-broadcast segmented reduce.
// N=262144 points, D=3, V=64, CAPACITY=2^20, table [CAPACITY,65] f32.

#define CAPACITY (1u << 20)
#define TBL_W 65
#define CHUNK 64

// ---------------- lattice math (validated round 0/1) ----------------
__device__ __forceinline__ void lattice_point(const float* __restrict__ pos, int point,
                                              uint32_t h[4], float w[4])
{
    const float scale0 = 2.3094010767585034f;
    const float scale1 = 1.3333333333333333f;
    const float scale2 = 0.9428090415820634f;

    const float cf0 = pos[point * 3 + 0] * scale0;
    const float cf1 = pos[point * 3 + 1] * scale1;
    const float cf2 = pos[point * 3 + 2] * scale2;

    const float t1 = cf2 + cf1;
    float elev[4];
    elev[0] = t1 + cf0;
    elev[1] = t1 - cf0;
    elev[2] = cf2 - 2.0f * cf1;
    elev[3] = -3.0f * cf2;

    float rem0[4];
    float rd_s = 0.0f;
#pragma unroll
    for (int j = 0; j < 4; ++j) {
        float rd = rintf(elev[j] * 0.25f);
        rem0[j] = rd * 4.0f;
        rd_s += rd;
    }
    const int rd_sum = (int)rd_s;

    float diff[4];
#pragma unroll
    for (int j = 0; j < 4; ++j) diff[j] = elev[j] - rem0[j];

    int rank[4];
#pragma unroll
    for (int i = 0; i < 4; ++i) {
        int r = 0;
#pragma unroll
        for (int j = 0; j < 4; ++j) {
            if (diff[j] > diff[i] || (diff[j] == diff[i] && j < i)) r++;
        }
        rank[i] = r + rd_sum;
    }

#pragma unroll
    for (int i = 0; i < 4; ++i) {
        if (rank[i] < 0)      { rank[i] += 4; rem0[i] += 4.0f; }
        else if (rank[i] > 3) { rank[i] -= 4; rem0[i] -= 4.0f; }
    }

    float delta[4];
#pragma unroll
    for (int i = 0; i < 4; ++i) delta[i] = (elev[i] - rem0[i]) * 0.25f;

    float b[5] = {0.f, 0.f, 0.f, 0.f, 0.f};
#pragma unroll
    for (int i = 0; i < 4; ++i) {
        int k1 = 3 - rank[i];
        int k2 = 4 - rank[i];
        if (k1 >= 0 && k1 < 5) b[k1] += delta[i];
        if (k2 >= 0 && k2 < 5) b[k2] -= delta[i];
    }
    w[0] = b[0] + (1.0f + b[4]);
    w[1] = b[1];
    w[2] = b[2];
    w[3] = b[3];

    const uint32_t P0 = 2654435761u, P1 = 805459861u, P2 = 3674653429u;
    const int k0  = (int)rem0[0];
    const int k1i = (int)rem0[1];
    const int k2i = (int)rem0[2];

#pragma unroll
    for (int r = 0; r < 4; ++r) {
        int o0 = (rank[0] < 4 - r) ? r : r - 4;
        int o1 = (rank[1] < 4 - r) ? r : r - 4;
        int o2 = (rank[2] < 4 - r) ? r : r - 4;
        uint32_t hh = (uint32_t)(k0 + o0)  * P0
                    + (uint32_t)(k1i + o1) * P1
                    + (uint32_t)(k2i + o2) * P2;
        h[r] = hh & (CAPACITY - 1u);
    }
}

// ---------------- pipeline kernels ----------------
__global__ __launch_bounds__(256) void k_hist(const float* __restrict__ pos,
                                              uint32_t* __restrict__ counts,
                                              int n, int Rmask)
{
    int p = blockIdx.x * blockDim.x + threadIdx.x;
    if (p >= n) return;
    uint32_t h[4]; float w[4];
    lattice_point(pos, p, h, w);
    const size_t repBase = (size_t)(p & Rmask) * CAPACITY;
#pragma unroll
    for (int r = 0; r < 4; ++r) atomicAdd(&counts[repBase + h[r]], 1u);
}

__global__ __launch_bounds__(256) void k_blocksum(const uint32_t* __restrict__ counts,
                                                  uint32_t* __restrict__ partials)
{
    __shared__ uint32_t s[256];
    const int b = blockIdx.x, t = threadIdx.x;
    uint4 v = ((const uint4*)(counts + (size_t)b * 1024))[t];
    s[t] = v.x + v.y + v.z + v.w;
    __syncthreads();
    for (int o = 128; o > 0; o >>= 1) {
        if (t < o) s[t] += s[t + o];
        __syncthreads();
    }
    if (t == 0) partials[b] = s[0];
}

// Exclusive scan of npart (= 1024*R <= 8192) partials, single block of 1024.
__global__ __launch_bounds__(1024) void k_scanpartials(uint32_t* __restrict__ partials,
                                                       int npart)
{
    __shared__ uint32_t s[1024];
    const int t = threadIdx.x;
    const int k = npart >> 10;           // elems per thread (1..8)
    uint32_t v[8];
    uint32_t tot = 0;
    for (int j = 0; j < k; ++j) { v[j] = partials[t * k + j]; tot += v[j]; }
    s[t] = tot;
    __syncthreads();
    for (int o = 1; o < 1024; o <<= 1) {
        uint32_t x = s[t];
        uint32_t y = (t >= o) ? s[t - o] : 0u;
        __syncthreads();
        s[t] = x + y;
        __syncthreads();
    }
    uint32_t run = (t > 0) ? s[t - 1] : 0u;
    for (int j = 0; j < k; ++j) {
        uint32_t tmp = v[j];
        partials[t * k + j] = run;
        run += tmp;
    }
}

// Fused: per-bin exclusive offsets + chunked worklist emission.
// One global cursor atomicAdd PER BLOCK (LDS-aggregated), not per bin.
__global__ __launch_bounds__(256) void k_offsets_worklist(
    const uint32_t* __restrict__ counts,
    const uint32_t* __restrict__ partials,
    uint32_t* __restrict__ offsets,
    uint4* __restrict__ work,
    uint32_t* __restrict__ cursor,
    uint32_t wcap)
{
    __shared__ uint32_t s[256];
    __shared__ uint32_t wbase;
    const int b = blockIdx.x, t = threadIdx.x;
    uint4 v = ((const uint4*)(counts + (size_t)b * 1024))[t];
    const uint32_t s4 = v.x + v.y + v.z + v.w;
    s[t] = s4;
    __syncthreads();
    for (int o = 1; o < 256; o <<= 1) {
        uint32_t x = s[t];
        uint32_t y = (t >= o) ? s[t - o] : 0u;
        __syncthreads();
        s[t] = x + y;
        __syncthreads();
    }
    const uint32_t texcl = ((t > 0) ? s[t - 1] : 0u) + partials[b];
    uint4 o4;
    o4.x = texcl;
    o4.y = texcl + v.x;
    o4.z = o4.y + v.y;
    o4.w = o4.z + v.z;
    ((uint4*)(offsets + (size_t)b * 1024))[t] = o4;

    // chunk counts for this thread's 4 bins
    const uint32_t c0 = (v.x + CHUNK - 1) / CHUNK;
    const uint32_t c1 = (v.y + CHUNK - 1) / CHUNK;
    const uint32_t c2 = (v.z + CHUNK - 1) / CHUNK;
    const uint32_t c3 = (v.w + CHUNK - 1) / CHUNK;
    const uint32_t nch = c0 + c1 + c2 + c3;
    __syncthreads();                 // protect s[] reuse
    s[t] = nch;
    __syncthreads();
    for (int o = 1; o < 256; o <<= 1) {
        uint32_t x = s[t];
        uint32_t y = (t >= o) ? s[t - o] : 0u;
        __syncthreads();
        s[t] = x + y;
        __syncthreads();
    }
    if (t == 255) wbase = (s[255] > 0) ? atomicAdd(cursor, s[255]) : 0u;
    __syncthreads();
    if (nch == 0) return;
    uint32_t idx = wbase + ((t > 0) ? s[t - 1] : 0u);

    const uint32_t lin0 = (uint32_t)b * 1024u + (uint32_t)t * 4u;
    const uint32_t cnts[4]   = { v.x, v.y, v.z, v.w };
    const uint32_t starts[4] = { o4.x, o4.y, o4.z, o4.w };
#pragma unroll
    for (int j = 0; j < 4; ++j) {
        uint32_t cnt = cnts[j];
        if (cnt == 0) continue;
        const uint32_t h = (lin0 + j) & (CAPACITY - 1u);
        uint32_t cs = starts[j];
        const uint32_t ce_all = cs + cnt;
        while (cs < ce_all) {
            uint32_t ce = min(cs + (uint32_t)CHUNK, ce_all);
            if (idx < wcap) work[idx] = make_uint4(h, cs, ce, 0u);
            ++idx;
            cs = ce;
        }
    }
}

// Scatter (w, pid) into sorted position; atomicSub consumes counts.
__global__ __launch_bounds__(256) void k_scatter(const float* __restrict__ pos,
                                                 const uint32_t* __restrict__ offsets,
                                                 uint32_t* __restrict__ counts,
                                                 uint2* __restrict__ wp_s,
                                                 int n, int Rmask)
{
    int p = blockIdx.x * blockDim.x + threadIdx.x;
    if (p >= n) return;
    uint32_t h[4]; float w[4];
    lattice_point(pos, p, h, w);
    const size_t repBase = (size_t)(p & Rmask) * CAPACITY;
#pragma unroll
    for (int r = 0; r < 4; ++r) {
        const size_t lin = repBase + h[r];
        uint32_t slot = atomicSub(&counts[lin], 1u) - 1u;
        uint32_t dst  = offsets[lin] + slot;
        uint2 wp;
        wp.x = __float_as_uint(w[r]);
        wp.y = (uint32_t)p;
        wp_s[dst] = wp;
    }
}

// One wave per chunk (<=64 entries). Coalesced wp load (lane e = entry e),
// shfl-broadcast; 8-deep independent vals gathers; one atomic flush per chunk.
__global__ __launch_bounds__(256) void k_reduce(const uint4* __restrict__ work,
                                                const uint32_t* __restrict__ cursor,
                                                const uint2* __restrict__ wp_s,
                                                const float* __restrict__ vals,
                                                float* __restrict__ table,
                                                uint32_t wcap)
{
    const int gtid   = blockIdx.x * blockDim.x + threadIdx.x;
    const int wid    = gtid >> 6;
    const int lane   = threadIdx.x & 63;
    const int nwaves = (gridDim.x * blockDim.x) >> 6;
    const uint32_t nwork = min(*cursor, wcap);

    for (uint32_t it = wid; it < nwork; it += nwaves) {
        const uint4 wi = work[it];
        const uint32_t h   = wi.x;
        const uint32_t cnt = wi.z - wi.y;

        uint2 wp = make_uint2(0u, 0u);
        if (lane < (int)cnt) wp = wp_s[wi.y + lane];
        const float    mywgt = __uint_as_float(wp.x);
        const int      mypid = (int)wp.y;

        float acc = 0.0f, acc1 = 0.0f;
        uint32_t e = 0;
        for (; e + 8 <= cnt; e += 8) {
#pragma unroll
            for (int j = 0; j < 8; ++j) {
                const float wj = __shfl(mywgt, (int)(e + j));
                const int   pj = __shfl(mypid, (int)(e + j));
                acc  += wj * vals[(size_t)pj * 64 + lane];
                acc1 += wj;
            }
        }
        for (; e < cnt; ++e) {
            const float wj = __shfl(mywgt, (int)e);
            const int   pj = __shfl(mypid, (int)e);
            acc  += wj * vals[(size_t)pj * 64 + lane];
            acc1 += wj;
        }
        atomicAdd(&table[(size_t)h * TBL_W + lane], acc);
        if (lane == 0) atomicAdd(&table[(size_t)h * TBL_W + 64], acc1);
    }
}

// ---------------- round-0 fallback ----------------
__global__ __launch_bounds__(256) void splat_fallback(const float* __restrict__ pos,
                                                      const float* __restrict__ vals,
                                                      float* __restrict__ table, int n)
{
    const int gtid  = blockIdx.x * blockDim.x + threadIdx.x;
    const int point = gtid >> 6;
    const int lane  = threadIdx.x & 63;
    if (point >= n) return;
    uint32_t h[4]; float w[4];
    lattice_point(pos, point, h, w);
    const float v = vals[(size_t)point * 64 + lane];
#pragma unroll
    for (int r = 0; r < 4; ++r)
        atomicAdd(&table[(size_t)h[r] * TBL_W + lane], w[r] * v);
    if (lane == 0) {
#pragma unroll
        for (int r = 0; r < 4; ++r)
            atomicAdd(&table[(size_t)h[r] * TBL_W + 64], w[r]);
    }
}

// ---------------- host launch ----------------
extern "C" void kernel_launch(void* const* d_in, const int* in_sizes, int n_in,
                              void* d_out, int out_size, void* d_ws, size_t ws_size,
                              hipStream_t stream) {
    const float* pos  = (const float*)d_in[0];
    const float* vals = (const float*)d_in[1];
    float* table      = (float*)d_out;

    const int n = in_sizes[0] / 3;        // 262144
    const uint32_t M = (uint32_t)n * 4;   // 1,048,576

    hipMemsetAsync(d_out, 0, (size_t)out_size * sizeof(float), stream);

    // Choose replication R; worklist capacity is a true upper bound:
    // #chunks <= #nonempty bins + M/CHUNK <= M + M/CHUNK.
    int R = 0;
    uint32_t wcap = 0;
    size_t offCnt = 0, offCur = 0, offOff = 0, offPart = 0, offWp = 0, offWork = 0;
    const uint32_t wcapFull = M + M / CHUNK;
    for (int tryR = 8; tryR >= 1; tryR >>= 1) {
        size_t L = (size_t)CAPACITY * tryR;
        size_t o0 = 0;                       // counts: L*4
        size_t o1 = o0 + L * 4;              // cursor: 64
        size_t o2 = o1 + 64;                 // offsets: L*4
        size_t o3 = o2 + L * 4;              // partials: (L/1024)*4
        size_t o4 = o3 + (L / 1024) * 4;     // wp_s: M*8
        size_t o5 = o4 + (size_t)M * 8;      // work: wcap*16
        size_t need = o5 + (size_t)wcapFull * 16;
        if (need <= ws_size) {
            R = tryR; wcap = wcapFull;
            offCnt = o0; offCur = o1; offOff = o2; offPart = o3; offWp = o4; offWork = o5;
            break;
        }
    }

    if (!R) {
        const int blocks = (n * 64 + 255) / 256;
        splat_fallback<<<blocks, 256, 0, stream>>>(pos, vals, table, n);
        return;
    }

    uint8_t* ws = (uint8_t*)d_ws;
    uint32_t* counts   = (uint32_t*)(ws + offCnt);
    uint32_t* cursor   = (uint32_t*)(ws + offCur);
    uint32_t* offsets  = (uint32_t*)(ws + offOff);
    uint32_t* partials = (uint32_t*)(ws + offPart);
    uint2*    wp_s     = (uint2*)   (ws + offWp);
    uint4*    work     = (uint4*)   (ws + offWork);

    const uint32_t L = (uint32_t)CAPACITY * R;
    const int Rmask = R - 1;

    hipMemsetAsync(ws, 0, (size_t)L * 4 + 64, stream);   // counts + cursor

    const int ptBlocks = (n + 255) / 256;
    k_hist<<<ptBlocks, 256, 0, stream>>>(pos, counts, n, Rmask);

    const int scanBlocks = L / 1024;
    k_blocksum        <<<scanBlocks, 256,  0, stream>>>(counts, partials);
    k_scanpartials    <<<1,          1024, 0, stream>>>(partials, scanBlocks);
    k_offsets_worklist<<<scanBlocks, 256,  0, stream>>>(counts, partials, offsets,
                                                        work, cursor, wcap);

    k_scatter<<<ptBlocks, 256, 0, stream>>>(pos, offsets, counts, wp_s, n, Rmask);

    k_reduce<<<4096, 256, 0, stream>>>(work, cursor, wp_s, vals, table, wcap);
}